// Round 1
// baseline (46.899 us; speedup 1.0000x reference)
//
#include <hip/hip_runtime.h>

#define SDF_THR 5e-5f
#define TRACE_ITERS 10
#define N_STEPS 100
#define N_ROOTFIND 8

__device__ __forceinline__ float norm3f(float x, float y, float z) {
    return sqrtf(x * x + y * y + z * z);
}

__global__ __launch_bounds__(256) void raytrace_kernel(
    const float* __restrict__ cam, const float* __restrict__ ray,
    float* __restrict__ out, int N, int R)
{
    int gid = blockIdx.x * blockDim.x + threadIdx.x;
    if (gid >= R) return;
    int b = gid / N;

    float cx = cam[b * 3 + 0], cy = cam[b * 3 + 1], cz = cam[b * 3 + 2];
    float rx = ray[gid * 3 + 0], ry = ray[gid * 3 + 1], rz = ray[gid * 3 + 2];

    // ---- sphere intersections (OBJ_R = 5) ----
    float rcd  = rx * cx + ry * cy + rz * cz;
    float cam2 = cx * cx + cy * cy + cz * cz;
    float under = rcd * rcd - (cam2 - 25.0f);
    bool  m0 = under > 0.0f;
    float sq = sqrtf(m0 ? under : 1.0f);
    float nearv = m0 ? fmaxf(-sq - rcd, 0.0f) : 0.0f;
    float farv  = m0 ? fmaxf( sq - rcd, 0.0f) : 0.0f;

    // ---- sphere tracing ----
    bool  unf_s = m0, unf_e = m0;
    float acc_s = m0 ? nearv : 0.0f;
    float acc_e = m0 ? farv  : 0.0f;
    float psx = m0 ? cx + acc_s * rx : 0.0f;
    float psy = m0 ? cy + acc_s * ry : 0.0f;
    float psz = m0 ? cz + acc_s * rz : 0.0f;
    float pex = m0 ? cx + acc_e * rx : 0.0f;
    float pey = m0 ? cy + acc_e * ry : 0.0f;
    float pez = m0 ? cz + acc_e * rz : 0.0f;
    float next_s = unf_s ? norm3f(psx, psy, psz) - 1.0f : 0.0f;
    float next_e = unf_e ? norm3f(pex, pey, pez) - 1.0f : 0.0f;

    #pragma unroll 1
    for (int i = 0; i < TRACE_ITERS; ++i) {
        float cur_s = unf_s ? next_s : 0.0f;
        cur_s = (cur_s <= SDF_THR) ? 0.0f : cur_s;
        float cur_e = unf_e ? next_e : 0.0f;
        cur_e = (cur_e <= SDF_THR) ? 0.0f : cur_e;
        unf_s = unf_s && (cur_s > SDF_THR);
        unf_e = unf_e && (cur_e > SDF_THR);
        acc_s += cur_s;
        acc_e -= cur_e;
        psx = cx + acc_s * rx; psy = cy + acc_s * ry; psz = cz + acc_s * rz;
        pex = cx + acc_e * rx; pey = cy + acc_e * ry; pez = cz + acc_e * rz;
        next_s = unf_s ? norm3f(psx, psy, psz) - 1.0f : 0.0f;
        next_e = unf_e ? norm3f(pex, pey, pez) - 1.0f : 0.0f;
        float cos_s = rx * psx + ry * psy + rz * psz;
        float cos_e = rx * pex + ry * pey + rz * pez;
        bool np_s = (next_s < 0.0f) || (cos_s > 0.0f);
        bool np_e = (next_e < 0.0f) || (cos_e < 0.0f);
        // masked line search back-off (LINE_STEP_ITERS = 1, step = 0.9)
        if (np_s) acc_s -= 0.9f * cur_s;
        if (np_e) acc_e += 0.9f * cur_e;
        psx = cx + acc_s * rx; psy = cy + acc_s * ry; psz = cz + acc_s * rz;
        pex = cx + acc_e * rx; pey = cy + acc_e * ry; pez = cz + acc_e * rz;
        if (np_s) next_s = norm3f(psx, psy, psz) - 1.0f;
        if (np_e) next_e = norm3f(pex, pey, pez) - 1.0f;
        unf_s = unf_s && (acc_s < acc_e);
        unf_e = unf_e && (acc_s < acc_e);
    }
    // final mask refresh
    {
        float cur_s = unf_s ? next_s : 0.0f;
        cur_s = (cur_s <= SDF_THR) ? 0.0f : cur_s;
        unf_s = unf_s && (cur_s > SDF_THR);
    }

    // ---- _forward glue ----
    bool  net_obj = acc_s < acc_e;
    float out_px = psx, out_py = psy, out_pz = psz;
    float out_d  = acc_s;
    bool  out_m  = net_obj;

    if (unf_s) {
        // ---- ray sampler (smask = true here; object_mask provably dead) ----
        float smin = acc_s, smax = acc_e;
        float dz = smax - smin;

        int   idx = 0;            // argmin of sign(sdf) * countdown (first occurrence)
        float best_tmp = 3.4e38f;
        float z_idx = 0.0f, sdf_idx = 0.0f;
        float best_sdf = 3.4e38f; // argmin of sdf (first occurrence)
        float z_out = 0.0f;

        #pragma unroll 1
        for (int k = 0; k < N_STEPS; ++k) {
            float t = (float)k / 99.0f;       // linspace(0,1,100)
            float z = smin + t * dz;
            float px = cx + z * rx, py = cy + z * ry, pz = cz + z * rz;
            float sv = norm3f(px, py, pz) - 1.0f;
            float sgn = (sv > 0.0f) ? 1.0f : ((sv < 0.0f) ? -1.0f : 0.0f);
            float tmp = sgn * (float)(N_STEPS - k);
            if (tmp < best_tmp) { best_tmp = tmp; idx = k; z_idx = z; sdf_idx = sv; }
            if (sv  < best_sdf) { best_sdf = sv; z_out = z; }
        }

        bool net_surface = sdf_idx < 0.0f;
        if (net_surface) {
            // bisection root-find between samples idx-1 and idx
            int klo = (idx - 1 > 0) ? (idx - 1) : 0;
            float tlo = (float)klo / 99.0f;
            float lo = smin + tlo * dz;
            float hi = z_idx;
            #pragma unroll
            for (int it = 0; it < N_ROOTFIND; ++it) {
                float mid = 0.5f * (lo + hi);
                float sm = norm3f(cx + mid * rx, cy + mid * ry, cz + mid * rz) - 1.0f;
                if (sm > 0.0f) lo = mid; else hi = mid;
            }
            float zr = 0.5f * (lo + hi);
            out_d  = zr;
            out_px = cx + zr * rx; out_py = cy + zr * ry; out_pz = cz + zr * rz;
            out_m  = true;
        } else {
            // no network surface: min-sdf point along the ray
            out_d  = z_out;
            out_px = cx + z_out * rx; out_py = cy + z_out * ry; out_pz = cz + z_out * rz;
            out_m  = false;
        }
    }

    // ---- outputs: pts [R,3] | net_obj [R] | acc_s [R] ----
    out[gid * 3 + 0] = out_px;
    out[gid * 3 + 1] = out_py;
    out[gid * 3 + 2] = out_pz;
    out[(size_t)R * 3 + gid] = out_m ? 1.0f : 0.0f;
    out[(size_t)R * 4 + gid] = out_d;
}

extern "C" void kernel_launch(void* const* d_in, const int* in_sizes, int n_in,
                              void* d_out, int out_size, void* d_ws, size_t ws_size,
                              hipStream_t stream) {
    const float* cam = (const float*)d_in[0];
    const float* ray = (const float*)d_in[1];
    int B = in_sizes[0] / 3;
    int R = in_sizes[1] / 3;
    int N = R / B;
    int threads = 256;
    int blocks = (R + threads - 1) / threads;
    raytrace_kernel<<<blocks, threads, 0, stream>>>(cam, ray, (float*)d_out, N, R);
}

// Round 2
// 20.542 us; speedup vs baseline: 2.2830x; 2.2830x over previous
//
#include <hip/hip_runtime.h>

#define SDF_THR 5e-5f
#define TRACE_ITERS 10
#define N_STEPS 100
#define N_ROOTFIND 8

// correctly-rounded k/99.0f without the v_div sequence (Markstein 2-fma refinement)
__device__ __forceinline__ float div99(int k) {
    const float c = 1.0f / 99.0f;
    float fk = (float)k;
    float t0 = fk * c;
    float e  = fmaf(t0, -99.0f, fk);
    return fmaf(e, c, t0);
}

__global__ __launch_bounds__(256) void raytrace_kernel(
    const float* __restrict__ cam, const float* __restrict__ ray,
    float* __restrict__ out, int N, int R)
{
    int gid = blockIdx.x * blockDim.x + threadIdx.x;
    if (gid >= R) return;
    int b = gid / N;

    float cx = cam[b * 3 + 0], cy = cam[b * 3 + 1], cz = cam[b * 3 + 2];
    float rx = ray[(size_t)gid * 3 + 0], ry = ray[(size_t)gid * 3 + 1], rz = ray[(size_t)gid * 3 + 2];

    // |cam + a*ray|^2 = a^2 + 2a*rcd + cam2  (|ray| = 1)
    float rcd  = rx * cx + ry * cy + rz * cz;
    float cam2 = cx * cx + cy * cy + cz * cz;
    float trcd = rcd + rcd;

    // ---- sphere intersections (OBJ_R = 5) ----
    float under = rcd * rcd - (cam2 - 25.0f);
    bool  m0 = under > 0.0f;
    float sq = sqrtf(m0 ? under : 1.0f);
    float nearv = m0 ? fmaxf(-sq - rcd, 0.0f) : 0.0f;
    float farv  = m0 ? fmaxf( sq - rcd, 0.0f) : 0.0f;

    auto sdfq = [&](float a) {
        float q = fmaf(a, a + trcd, cam2);
        return sqrtf(fmaxf(q, 0.0f)) - 1.0f;   // fmax: guard fma rounding negative
    };

    // ---- sphere tracing ----
    bool  unf_s = m0, unf_e = m0;
    float acc_s = nearv, acc_e = farv;         // m0 false -> both already 0
    float next_s = unf_s ? sdfq(acc_s) : 0.0f;
    float next_e = unf_e ? sdfq(acc_e) : 0.0f;

    #pragma unroll 1
    for (int i = 0; i < TRACE_ITERS; ++i) {
        float cur_s = unf_s ? next_s : 0.0f;
        cur_s = (cur_s <= SDF_THR) ? 0.0f : cur_s;
        float cur_e = unf_e ? next_e : 0.0f;
        cur_e = (cur_e <= SDF_THR) ? 0.0f : cur_e;
        unf_s = unf_s && (cur_s > SDF_THR);
        unf_e = unf_e && (cur_e > SDF_THR);
        acc_s += cur_s;
        acc_e -= cur_e;
        next_s = unf_s ? sdfq(acc_s) : 0.0f;
        next_e = unf_e ? sdfq(acc_e) : 0.0f;
        float cos_s = rcd + acc_s;             // ray . (cam + acc*ray)
        float cos_e = rcd + acc_e;
        bool np_s = (next_s < 0.0f) || (cos_s > 0.0f);
        bool np_e = (next_e < 0.0f) || (cos_e < 0.0f);
        // line search back-off (LINE_STEP_ITERS = 1, step = 0.9)
        if (np_s) { acc_s -= 0.9f * cur_s; next_s = sdfq(acc_s); }
        if (np_e) { acc_e += 0.9f * cur_e; next_e = sdfq(acc_e); }
        unf_s = unf_s && (acc_s < acc_e);
        unf_e = unf_e && (acc_s < acc_e);
    }
    // final mask refresh
    {
        float cur_s = unf_s ? next_s : 0.0f;
        cur_s = (cur_s <= SDF_THR) ? 0.0f : cur_s;
        unf_s = unf_s && (cur_s > SDF_THR);
    }

    // ---- defaults from trace ----
    bool  out_m = acc_s < acc_e;
    float out_d = acc_s;
    float out_px = fmaf(acc_s, rx, cx);
    float out_py = fmaf(acc_s, ry, cy);
    float out_pz = fmaf(acc_s, rz, cz);

    if (unf_s) {
        // ---- ray sampler: all decisions on q(z) vs 1 (sign(sdf) = sign(q-1)) ----
        float smin = acc_s, smax = acc_e;
        float dzr = smax - smin;

        int   kneg = N_STEPS;     // first sample with sdf < 0
        int   kqmin = 0;          // argmin of sdf == argmin of q (first occurrence)
        float qmin = 3.4e38f;

        #pragma unroll 4
        for (int k = 0; k < N_STEPS; ++k) {
            float z = fmaf(div99(k), dzr, smin);
            float q = fmaf(z, z + trcd, cam2);
            if (q < 1.0f) kneg = min(kneg, k);
            if (q < qmin) { qmin = q; kqmin = k; }
        }

        bool net_surface = (kneg < N_STEPS);
        if (net_surface) {
            int klo = (kneg - 1 > 0) ? (kneg - 1) : 0;
            float lo = fmaf(div99(klo),  dzr, smin);
            float hi = fmaf(div99(kneg), dzr, smin);
            #pragma unroll
            for (int it = 0; it < N_ROOTFIND; ++it) {
                float mid = 0.5f * (lo + hi);
                float qm = fmaf(mid, mid + trcd, cam2);
                bool go_lo = qm > 1.0f;        // sdf(mid) > 0
                lo = go_lo ? mid : lo;
                hi = go_lo ? hi : mid;
            }
            float zr = 0.5f * (lo + hi);
            out_d = zr; out_m = true;
            out_px = fmaf(zr, rx, cx);
            out_py = fmaf(zr, ry, cy);
            out_pz = fmaf(zr, rz, cz);
        } else {
            float zo = fmaf(div99(kqmin), dzr, smin);
            out_d = zo; out_m = false;
            out_px = fmaf(zo, rx, cx);
            out_py = fmaf(zo, ry, cy);
            out_pz = fmaf(zo, rz, cz);
        }
    }

    // ---- outputs: pts [R,3] | net_obj [R] | acc_s [R] ----
    out[(size_t)gid * 3 + 0] = out_px;
    out[(size_t)gid * 3 + 1] = out_py;
    out[(size_t)gid * 3 + 2] = out_pz;
    out[(size_t)R * 3 + gid] = out_m ? 1.0f : 0.0f;
    out[(size_t)R * 4 + gid] = out_d;
}

extern "C" void kernel_launch(void* const* d_in, const int* in_sizes, int n_in,
                              void* d_out, int out_size, void* d_ws, size_t ws_size,
                              hipStream_t stream) {
    const float* cam = (const float*)d_in[0];
    const float* ray = (const float*)d_in[1];
    int B = in_sizes[0] / 3;
    int R = in_sizes[1] / 3;
    int N = R / B;
    int threads = 256;
    int blocks = (R + threads - 1) / threads;
    raytrace_kernel<<<blocks, threads, 0, stream>>>(cam, ray, (float*)d_out, N, R);
}